// Round 12
// baseline (251.946 us; speedup 1.0000x reference)
//
#include <hip/hip_runtime.h>
#include <cfloat>

#define DD 128
#define NLAYERS 3
#define NPB 128     // nodes per block in pool stage A
#define SCHUNK 1024 // elements per block in hierarchical scan

typedef short bf16x8 __attribute__((ext_vector_type(8)));
typedef float f32x4 __attribute__((ext_vector_type(4)));

// ---- bf16 helpers (RNE) ----
__device__ __forceinline__ unsigned short f2b(float f) {
    unsigned u = __float_as_uint(f);
    u += 0x7fffu + ((u >> 16) & 1u);
    return (unsigned short)(u >> 16);
}
__device__ __forceinline__ float b2f(unsigned short b) {
    return __uint_as_float(((unsigned)b) << 16);
}

// ---- monotonic float<->uint encoding for atomicMax on floats ----
__device__ __forceinline__ unsigned enc_f(float f) {
    unsigned b = __float_as_uint(f);
    return (b & 0x80000000u) ? ~b : (b | 0x80000000u);
}
__device__ __forceinline__ float dec_f(unsigned u) {
    return __uint_as_float((u & 0x80000000u) ? (u & 0x7fffffffu) : ~u);
}

// ========== conversion (x + W1 + W2) and workspace zeroing, ONE kernel ==========
__global__ void convert_init_kernel(const float* __restrict__ x_in,
                                    unsigned short* __restrict__ xb,
                                    const float* __restrict__ W1s, const float* __restrict__ W2s,
                                    unsigned short* __restrict__ Wb1s,
                                    unsigned short* __restrict__ Wb2s,
                                    int* __restrict__ deg,
                                    float* __restrict__ ps, unsigned* __restrict__ pmx,
                                    int* __restrict__ cnt,
                                    int n4, int nN, int nBD, int nB, int per, int xbBlocks) {
    if ((int)blockIdx.x < xbBlocks) {
        int i = blockIdx.x * 256 + threadIdx.x;
        if (i < n4) {
            float4 v = ((const float4*)x_in)[i];
            ushort4 b;
            b.x = f2b(v.x); b.y = f2b(v.y); b.z = f2b(v.z); b.w = f2b(v.w);
            ((ushort4*)xb)[i] = b;
        }
        if (i < nN) deg[i] = 0;
        if (i < nBD) { ps[i] = 0.f; pmx[i] = 0u; }   // 0 < enc(any finite)
        if (i < nB) cnt[i] = 0;
    } else {
        int idx = (blockIdx.x - xbBlocks) * 256 + threadIdx.x;
        if (idx >= 2 * per) return;
        const float* W = (idx < per) ? W1s : W2s;
        unsigned short* Wb = (idx < per) ? Wb1s : Wb2s;
        if (idx >= per) idx -= per;
        int lane = idx & 63;
        int rest = idx >> 6;
        int ks = rest & 3; rest >>= 2;
        int nt = rest & 7;
        int l  = rest >> 3;
        int n = nt * 16 + (lane & 15);
        int kbase = ks * 32 + (lane >> 4) * 8;
        const float* Wl = W + (size_t)l * DD * DD;
        unsigned short* dst = Wb + (size_t)l * DD * DD + ((size_t)(nt * 4 + ks) * 64 + lane) * 8;
#pragma unroll
        for (int j = 0; j < 8; ++j) dst[j] = f2b(Wl[(size_t)(kbase + j) * DD + n]);
    }
}

// ================= CSR build =================

__global__ void deg_kernel(const int* __restrict__ dst, int* __restrict__ deg, int nE) {
    int e = blockIdx.x * blockDim.x + threadIdx.x;
    if (e < nE) atomicAdd(&deg[dst[e]], 1);
}

__global__ __launch_bounds__(256) void scan_sum_kernel(const int* __restrict__ deg,
                                                       int* __restrict__ bsum, int nN) {
    int t = threadIdx.x;
    int base = blockIdx.x * SCHUNK + t * 4;
    int v = 0;
#pragma unroll
    for (int k = 0; k < 4; ++k) { int i = base + k; if (i < nN) v += deg[i]; }
    for (int off = 32; off; off >>= 1) v += __shfl_down(v, off, 64);
    __shared__ int wsum[4];
    if ((t & 63) == 0) wsum[t >> 6] = v;
    __syncthreads();
    if (t == 0) bsum[blockIdx.x] = wsum[0] + wsum[1] + wsum[2] + wsum[3];
}

__global__ __launch_bounds__(256) void scan_apply_kernel(const int* __restrict__ deg,
                                                         const int* __restrict__ bsum,
                                                         int* __restrict__ row_ptr,
                                                         int nN, int G) {
    __shared__ int sh[256];
    __shared__ int sh2[256];
    int t = threadIdx.x;
    int base = blockIdx.x * SCHUNK + t * 4;
    int d0 = 0, d1 = 0, d2 = 0, d3 = 0;
    if (base + 0 < nN) d0 = deg[base + 0];
    if (base + 1 < nN) d1 = deg[base + 1];
    if (base + 2 < nN) d2 = deg[base + 2];
    if (base + 3 < nN) d3 = deg[base + 3];
    int tsum = d0 + d1 + d2 + d3;
    sh[t] = tsum;
    sh2[t] = (t < G) ? bsum[t] : 0;
    __syncthreads();
    for (int off = 1; off < 256; off <<= 1) {
        int o  = (t >= off) ? sh[t - off]  : 0;
        int o2 = (t >= off) ? sh2[t - off] : 0;
        __syncthreads();
        sh[t] += o; sh2[t] += o2;
        __syncthreads();
    }
    int bb = (blockIdx.x > 0) ? sh2[blockIdx.x - 1] : 0;  // exclusive block offset
    int run = bb + sh[t] - tsum;
    if (base + 0 < nN) row_ptr[base + 0] = run;           run += d0;
    if (base + 1 < nN) row_ptr[base + 1] = run;           run += d1;
    if (base + 2 < nN) row_ptr[base + 2] = run;           run += d2;
    if (base + 3 < nN) row_ptr[base + 3] = run;
    if (blockIdx.x == G - 1 && t == 0) row_ptr[nN] = sh2[G - 1];
}

// slot = row_ptr[d] + atomicSub(deg[d]) - 1  (deg is dead after the scan; ends at 0)
__global__ void fill_kernel(const int* __restrict__ src, const int* __restrict__ dst,
                            const int* __restrict__ row_ptr, int* __restrict__ deg,
                            int* __restrict__ csr_src, int nE) {
    int e = blockIdx.x * blockDim.x + threadIdx.x;
    if (e >= nE) return;
    int d = dst[e];
    int pos = row_ptr[d] + atomicSub(&deg[d], 1) - 1;
    csr_src[pos] = src[e];
}

// ====== aggregation + combine (bf16, 32 lanes/node, 8-wide ILP, gate-specialized,
//        software-pipelined index loads) ======
// h0b = xb[n] + (za0 + za1/degc) * sum + za2 * (deg>0 ? max : 0)
__global__ __launch_bounds__(256) void agg_combine_kernel(const unsigned short* __restrict__ xb,
                                                          const int* __restrict__ csr_src,
                                                          const int* __restrict__ row_ptr,
                                                          const float* __restrict__ z_agg_l,
                                                          unsigned short* __restrict__ h0b,
                                                          int nN) {
    int t = threadIdx.x;
    int n = blockIdx.x * 8 + (t >> 5);
    if (n >= nN) return;
    int q = t & 31;
    int start = row_ptr[n], end = row_ptr[n + 1];
    float za0 = z_agg_l[0], za1 = z_agg_l[1], za2 = z_agg_l[2];
    bool need_sum = (za0 != 0.0f) || (za1 != 0.0f);
    bool need_max = (za2 != 0.0f);

    const ushort4* tab = (const ushort4*)xb;
    float4 sum = make_float4(0.f, 0.f, 0.f, 0.f);
    float4 mx  = make_float4(-FLT_MAX, -FLT_MAX, -FLT_MAX, -FLT_MAX);
    int last = end - 1;

#define CL(i) ((i) <= last ? (i) : last)
#define LOADI(a,b,c,d,e_,f,g,h, base) \
    a = csr_src[CL((base) + 0)]; b = csr_src[CL((base) + 1)]; \
    c = csr_src[CL((base) + 2)]; d = csr_src[CL((base) + 3)]; \
    e_ = csr_src[CL((base) + 4)]; f = csr_src[CL((base) + 5)]; \
    g = csr_src[CL((base) + 6)]; h = csr_src[CL((base) + 7)];
#define GATHER8() \
    ushort4 v0 = tab[(size_t)i0 * 32 + q]; ushort4 v1 = tab[(size_t)i1 * 32 + q]; \
    ushort4 v2 = tab[(size_t)i2 * 32 + q]; ushort4 v3 = tab[(size_t)i3 * 32 + q]; \
    ushort4 v4 = tab[(size_t)i4 * 32 + q]; ushort4 v5 = tab[(size_t)i5 * 32 + q]; \
    ushort4 v6 = tab[(size_t)i6 * 32 + q]; ushort4 v7 = tab[(size_t)i7 * 32 + q];
#define ROT() i0=j0; i1=j1; i2=j2; i3=j3; i4=j4; i5=j5; i6=j6; i7=j7;

#define ACCS(vb, ok) { float ax=b2f(vb.x),ay=b2f(vb.y),az=b2f(vb.z),aw=b2f(vb.w); \
                       if (ok) { sum.x+=ax;sum.y+=ay;sum.z+=az;sum.w+=aw; } }
#define ACCM(vb)     { float ax=b2f(vb.x),ay=b2f(vb.y),az=b2f(vb.z),aw=b2f(vb.w); \
                       mx.x=fmaxf(mx.x,ax);mx.y=fmaxf(mx.y,ay); \
                       mx.z=fmaxf(mx.z,az);mx.w=fmaxf(mx.w,aw); }
#define ACCB(vb, ok) { float ax=b2f(vb.x),ay=b2f(vb.y),az=b2f(vb.z),aw=b2f(vb.w); \
                       mx.x=fmaxf(mx.x,ax);mx.y=fmaxf(mx.y,ay); \
                       mx.z=fmaxf(mx.z,az);mx.w=fmaxf(mx.w,aw); \
                       if (ok) { sum.x+=ax;sum.y+=ay;sum.z+=az;sum.w+=aw; } }

    if (start <= last) {
        int i0,i1,i2,i3,i4,i5,i6,i7;
        LOADI(i0,i1,i2,i3,i4,i5,i6,i7, start)
        if (need_sum && !need_max) {
            for (int e = start; e <= last; e += 8) {
                int j0,j1,j2,j3,j4,j5,j6,j7;
                LOADI(j0,j1,j2,j3,j4,j5,j6,j7, e + 8)   // next batch, clamped
                GATHER8()
                ACCS(v0, true)
                ACCS(v1, e + 1 <= last)
                ACCS(v2, e + 2 <= last)
                ACCS(v3, e + 3 <= last)
                ACCS(v4, e + 4 <= last)
                ACCS(v5, e + 5 <= last)
                ACCS(v6, e + 6 <= last)
                ACCS(v7, e + 7 <= last)
                ROT()
            }
        } else if (need_max && !need_sum) {
            for (int e = start; e <= last; e += 8) {
                int j0,j1,j2,j3,j4,j5,j6,j7;
                LOADI(j0,j1,j2,j3,j4,j5,j6,j7, e + 8)
                GATHER8()
                ACCM(v0) ACCM(v1) ACCM(v2) ACCM(v3)   // duplicates are max-safe
                ACCM(v4) ACCM(v5) ACCM(v6) ACCM(v7)
                ROT()
            }
        } else {
            for (int e = start; e <= last; e += 8) {
                int j0,j1,j2,j3,j4,j5,j6,j7;
                LOADI(j0,j1,j2,j3,j4,j5,j6,j7, e + 8)
                GATHER8()
                ACCB(v0, true)
                ACCB(v1, e + 1 <= last)
                ACCB(v2, e + 2 <= last)
                ACCB(v3, e + 3 <= last)
                ACCB(v4, e + 4 <= last)
                ACCB(v5, e + 5 <= last)
                ACCB(v6, e + 6 <= last)
                ACCB(v7, e + 7 <= last)
                ROT()
            }
        }
    }
#undef CL
#undef LOADI
#undef GATHER8
#undef ROT
#undef ACCS
#undef ACCM
#undef ACCB

    int degn = end - start;
    float inv = 1.0f / fmaxf((float)degn, 1.0f);
    float c01 = za0 + za1 * inv;
    bool nb = (degn > 0) && need_max;     // keep -FLT_MAX sentinel out
    ushort4 sb = tab[(size_t)n * 32 + q];
    ushort4 r;
    r.x = f2b(b2f(sb.x) + c01 * sum.x + za2 * (nb ? mx.x : 0.f));
    r.y = f2b(b2f(sb.y) + c01 * sum.y + za2 * (nb ? mx.y : 0.f));
    r.z = f2b(b2f(sb.z) + c01 * sum.z + za2 * (nb ? mx.z : 0.f));
    r.w = f2b(b2f(sb.w) + c01 * sum.w + za2 * (nb ? mx.w : 0.f));
    ((ushort4*)(h0b + (size_t)n * DD))[q] = r;
}

// ================= fused FFN: xb_out = xb_in + relu(relu(h0@W1+b1)@W2+b2) ======
// Block = 64 rows, 4 waves, each wave owns a 16-row strip.
// LDS union (32 KiB): first 16 KiB = h1 bf16 [64 x 256B]; whole = v f32 [64 x 512B].
__global__ __launch_bounds__(256) void fused_ffn_kernel(
        const unsigned short* __restrict__ h0b,
        const unsigned short* __restrict__ Wb1, const float* __restrict__ b1,
        const unsigned short* __restrict__ Wb2, const float* __restrict__ b2,
        const unsigned short* __restrict__ xb_in,
        unsigned short* __restrict__ xb_out, int M) {
    __shared__ char lds[64 * DD * 4];        // 32 KiB union

    int t = threadIdx.x;
    int lane = t & 63;
    int w = t >> 6;
    int row0 = blockIdx.x * 64;
    int ar = row0 + w * 16 + (lane & 15);
    if (ar > M - 1) ar = M - 1;              // clamp loads; epilogue guards stores
    int g = lane >> 4;                       // k-group 0..3
    int colw = lane & 15;
    int rbl = w * 16 + g * 4;                // local C-row base

    const unsigned short* Ap = h0b + (size_t)ar * DD + g * 8;
    bf16x8 a0 = *(const bf16x8*)(Ap);
    bf16x8 a1 = *(const bf16x8*)(Ap + 32);
    bf16x8 a2 = *(const bf16x8*)(Ap + 64);
    bf16x8 a3 = *(const bf16x8*)(Ap + 96);

    // ---- GEMM1 -> h1 (bf16, LDS, swizzled) ----
    const bf16x8* Wv1 = (const bf16x8*)Wb1;
#pragma unroll
    for (int nt = 0; nt < 8; ++nt) {
        f32x4 acc = {0.f, 0.f, 0.f, 0.f};
        acc = __builtin_amdgcn_mfma_f32_16x16x32_bf16(a0, Wv1[(nt * 4 + 0) * 64 + lane], acc, 0, 0, 0);
        acc = __builtin_amdgcn_mfma_f32_16x16x32_bf16(a1, Wv1[(nt * 4 + 1) * 64 + lane], acc, 0, 0, 0);
        acc = __builtin_amdgcn_mfma_f32_16x16x32_bf16(a2, Wv1[(nt * 4 + 2) * 64 + lane], acc, 0, 0, 0);
        acc = __builtin_amdgcn_mfma_f32_16x16x32_bf16(a3, Wv1[(nt * 4 + 3) * 64 + lane], acc, 0, 0, 0);
        float bv = b1[nt * 16 + colw];
        int cb = (nt * 16 + colw) * 2;
#pragma unroll
        for (int i = 0; i < 4; ++i) {
            int r1 = rbl + i;
            *(unsigned short*)(lds + r1 * 256 + (cb ^ ((unsigned)(r1 & 7) << 4))) =
                f2b(fmaxf(acc[i] + bv, 0.f));
        }
    }

    // ---- h1 A-fragments from own strip (in-wave RAW through LDS) ----
    int rAl = w * 16 + (lane & 15);
    unsigned swA = (unsigned)(rAl & 7) << 4;
    const char* hA = lds + rAl * 256;
    bf16x8 c0 = *(const bf16x8*)(hA + ((g * 16 +   0) ^ swA));
    bf16x8 c1 = *(const bf16x8*)(hA + ((g * 16 +  64) ^ swA));
    bf16x8 c2 = *(const bf16x8*)(hA + ((g * 16 + 128) ^ swA));
    bf16x8 c3 = *(const bf16x8*)(hA + ((g * 16 + 192) ^ swA));
    __syncthreads();   // all c-frags loaded before v aliases h1 storage

    // ---- GEMM2 -> v = relu(h1@W2+b2) (f32, LDS, swizzled) ----
    const bf16x8* Wv2 = (const bf16x8*)Wb2;
#pragma unroll
    for (int nt = 0; nt < 8; ++nt) {
        f32x4 acc = {0.f, 0.f, 0.f, 0.f};
        acc = __builtin_amdgcn_mfma_f32_16x16x32_bf16(c0, Wv2[(nt * 4 + 0) * 64 + lane], acc, 0, 0, 0);
        acc = __builtin_amdgcn_mfma_f32_16x16x32_bf16(c1, Wv2[(nt * 4 + 1) * 64 + lane], acc, 0, 0, 0);
        acc = __builtin_amdgcn_mfma_f32_16x16x32_bf16(c2, Wv2[(nt * 4 + 2) * 64 + lane], acc, 0, 0, 0);
        acc = __builtin_amdgcn_mfma_f32_16x16x32_bf16(c3, Wv2[(nt * 4 + 3) * 64 + lane], acc, 0, 0, 0);
        float bv = b2[nt * 16 + colw];
        int cb = (nt * 16 + colw) * 4;
#pragma unroll
        for (int i = 0; i < 4; ++i) {
            int r1 = rbl + i;
            *(float*)(lds + r1 * 512 + (cb ^ ((unsigned)(r1 & 7) << 4))) =
                fmaxf(acc[i] + bv, 0.f);
        }
    }
    __syncthreads();

    // ---- coalesced epilogue: xb_out = bf16(xb_in + v) ----
    int q = t & 31;
    int grp = t >> 5;
    for (int pass = 0; pass < 8; ++pass) {
        int rr = pass * 8 + grp;
        int n = row0 + rr;
        if (n < M) {
            ushort4 xv = ((const ushort4*)(xb_in + (size_t)n * DD))[q];
            float4 vv = *(const float4*)(lds + rr * 512 + ((q * 16) ^ ((unsigned)(rr & 7) << 4)));
            ushort4 b;
            b.x = f2b(b2f(xv.x) + vv.x);
            b.y = f2b(b2f(xv.y) + vv.y);
            b.z = f2b(b2f(xv.z) + vv.z);
            b.w = f2b(b2f(xv.w) + vv.w);
            ((ushort4*)(xb_out + (size_t)n * DD))[q] = b;
        }
    }
}

// ================= global pooling, two-stage (bf16 input) =================
__global__ __launch_bounds__(256) void pool_partial_kernel(const unsigned short* __restrict__ xb,
                                                           const int* __restrict__ batch,
                                                           float* __restrict__ ps,
                                                           unsigned* __restrict__ pmx,
                                                           int* __restrict__ cnt, int nN) {
    int t = threadIdx.x;
    int q = t & 31;
    int p = t >> 5;
    int node0 = blockIdx.x * NPB;
    int nodeEnd = node0 + NPB; if (nodeEnd > nN) nodeEnd = nN;

    const ushort4* xv = (const ushort4*)xb;
    float4 sum = make_float4(0.f, 0.f, 0.f, 0.f);
    float4 mx  = make_float4(-FLT_MAX, -FLT_MAX, -FLT_MAX, -FLT_MAX);
    int count = 0, g_cur = -1;

    for (int row = node0 + p; row < nodeEnd; row += 8) {
        int g = batch[row];
        if (g != g_cur) {
            if (g_cur >= 0) {
                atomicAdd(&ps[(size_t)g_cur * DD + q * 4 + 0], sum.x);
                atomicAdd(&ps[(size_t)g_cur * DD + q * 4 + 1], sum.y);
                atomicAdd(&ps[(size_t)g_cur * DD + q * 4 + 2], sum.z);
                atomicAdd(&ps[(size_t)g_cur * DD + q * 4 + 3], sum.w);
                atomicMax(&pmx[(size_t)g_cur * DD + q * 4 + 0], enc_f(mx.x));
                atomicMax(&pmx[(size_t)g_cur * DD + q * 4 + 1], enc_f(mx.y));
                atomicMax(&pmx[(size_t)g_cur * DD + q * 4 + 2], enc_f(mx.z));
                atomicMax(&pmx[(size_t)g_cur * DD + q * 4 + 3], enc_f(mx.w));
                if (q == 0) atomicAdd(&cnt[g_cur], count);
            }
            sum = make_float4(0.f, 0.f, 0.f, 0.f);
            mx  = make_float4(-FLT_MAX, -FLT_MAX, -FLT_MAX, -FLT_MAX);
            count = 0; g_cur = g;
        }
        ushort4 vb = xv[(size_t)row * 32 + q];
        float vx = b2f(vb.x), vy = b2f(vb.y), vz = b2f(vb.z), vw = b2f(vb.w);
        sum.x += vx; sum.y += vy; sum.z += vz; sum.w += vw;
        mx.x = fmaxf(mx.x, vx); mx.y = fmaxf(mx.y, vy);
        mx.z = fmaxf(mx.z, vz); mx.w = fmaxf(mx.w, vw);
        count++;
    }
    if (g_cur >= 0) {
        atomicAdd(&ps[(size_t)g_cur * DD + q * 4 + 0], sum.x);
        atomicAdd(&ps[(size_t)g_cur * DD + q * 4 + 1], sum.y);
        atomicAdd(&ps[(size_t)g_cur * DD + q * 4 + 2], sum.z);
        atomicAdd(&ps[(size_t)g_cur * DD + q * 4 + 3], sum.w);
        atomicMax(&pmx[(size_t)g_cur * DD + q * 4 + 0], enc_f(mx.x));
        atomicMax(&pmx[(size_t)g_cur * DD + q * 4 + 1], enc_f(mx.y));
        atomicMax(&pmx[(size_t)g_cur * DD + q * 4 + 2], enc_f(mx.z));
        atomicMax(&pmx[(size_t)g_cur * DD + q * 4 + 3], enc_f(mx.w));
        if (q == 0) atomicAdd(&cnt[g_cur], count);
    }
}

__global__ void pool_final_kernel(const float* __restrict__ ps,
                                  const unsigned* __restrict__ pmx,
                                  const int* __restrict__ cnt,
                                  const float* __restrict__ z_pool,
                                  float* __restrict__ out, int total) {
    int i = blockIdx.x * blockDim.x + threadIdx.x;
    if (i >= total) return;
    int g = i >> 7;
    float zp0 = z_pool[0], zp1 = z_pool[1], zp2 = z_pool[2];
    int c = cnt[g];
    float s = ps[i];
    float pm = s / fmaxf((float)c, 1.0f);
    float pv = (c > 0) ? dec_f(pmx[i]) : 0.0f;
    out[i] = zp0 * s + zp1 * pm + zp2 * pv;
}

extern "C" void kernel_launch(void* const* d_in, const int* in_sizes, int n_in,
                              void* d_out, int out_size, void* d_ws, size_t ws_size,
                              hipStream_t stream) {
    const float* x_in   = (const float*)d_in[0];
    const int*   eidx   = (const int*)d_in[1];
    const int*   batch  = (const int*)d_in[2];
    const float* z_agg  = (const float*)d_in[3];
    const float* z_pool = (const float*)d_in[4];
    const float* W1     = (const float*)d_in[5];
    const float* b1     = (const float*)d_in[6];
    const float* W2     = (const float*)d_in[7];
    const float* b2     = (const float*)d_in[8];

    int nN = in_sizes[0] / DD;       // 50000
    int nE = in_sizes[1] / 2;        // 600000
    int nB = out_size / DD;          // 64
    const int* src = eidx;
    const int* dst = eidx + nE;

    char* p = (char*)d_ws;
    size_t nd = (size_t)nN * DD * sizeof(float);
    unsigned short* xb0 = (unsigned short*)p;  p += nd / 2;
    unsigned short* xbA = (unsigned short*)p;  p += nd / 2;
    unsigned short* h0b = (unsigned short*)p;  p += nd / 2;
    unsigned short* Wb1 = (unsigned short*)p;  p += (size_t)NLAYERS * DD * DD * 2;
    unsigned short* Wb2 = (unsigned short*)p;  p += (size_t)NLAYERS * DD * DD * 2;
    int* row_ptr = (int*)p;  p += (size_t)(nN + 1) * 4;
    int* deg     = (int*)p;  p += (size_t)nN * 4;
    int* csr_src = (int*)p;  p += (size_t)nE * 4 + 64;   // +64B slack
    float*    ps  = (float*)p;    p += (size_t)nB * DD * 4;
    unsigned* pmx = (unsigned*)p; p += (size_t)nB * DD * 4;
    int*      cnt = (int*)p;      p += (size_t)nB * 4;
    int*      bsum = (int*)p;

    int G = (nN + SCHUNK - 1) / SCHUNK;   // 49 for nN=50000

    // ---- conversion + zero-init (one launch) ----
    int n4 = nN * DD / 4;
    int per = NLAYERS * 8 * 4 * 64;
    int xbBlocks = (n4 + 255) / 256;
    int wBlocks = (2 * per + 255) / 256;
    convert_init_kernel<<<xbBlocks + wBlocks, 256, 0, stream>>>(
        x_in, xb0, W1, W2, Wb1, Wb2, deg, ps, pmx, cnt,
        n4, nN, nB * DD, nB, per, xbBlocks);

    // ---- CSR build (deg -> scan -> fill; fill consumes deg) ----
    deg_kernel<<<(nE + 255) / 256, 256, 0, stream>>>(dst, deg, nE);
    scan_sum_kernel<<<G, 256, 0, stream>>>(deg, bsum, nN);
    scan_apply_kernel<<<G, 256, 0, stream>>>(deg, bsum, row_ptr, nN, G);
    fill_kernel<<<(nE + 255) / 256, 256, 0, stream>>>(src, dst, row_ptr, deg, csr_src, nE);

    // ---- layers ----
    int agrid = (nN + 7) / 8;
    int fgrid = (nN + 63) / 64;
    // L0: xb0 -> xbA
    agg_combine_kernel<<<agrid, 256, 0, stream>>>(xb0, csr_src, row_ptr, z_agg + 0, h0b, nN);
    fused_ffn_kernel<<<fgrid, 256, 0, stream>>>(h0b, Wb1 + 0 * DD * DD, b1 + 0 * DD,
                                                Wb2 + 0 * DD * DD, b2 + 0 * DD,
                                                xb0, xbA, nN);
    // L1: xbA -> xb0
    agg_combine_kernel<<<agrid, 256, 0, stream>>>(xbA, csr_src, row_ptr, z_agg + 3, h0b, nN);
    fused_ffn_kernel<<<fgrid, 256, 0, stream>>>(h0b, Wb1 + 1 * DD * DD, b1 + 1 * DD,
                                                Wb2 + 1 * DD * DD, b2 + 1 * DD,
                                                xbA, xb0, nN);
    // L2: xb0 -> xbA
    agg_combine_kernel<<<agrid, 256, 0, stream>>>(xb0, csr_src, row_ptr, z_agg + 6, h0b, nN);
    fused_ffn_kernel<<<fgrid, 256, 0, stream>>>(h0b, Wb1 + 2 * DD * DD, b1 + 2 * DD,
                                                Wb2 + 2 * DD * DD, b2 + 2 * DD,
                                                xb0, xbA, nN);

    // ---- pooling ----
    pool_partial_kernel<<<(nN + NPB - 1) / NPB, 256, 0, stream>>>(xbA, batch, ps, pmx, cnt, nN);
    pool_final_kernel<<<(nB * DD + 255) / 256, 256, 0, stream>>>(ps, pmx, cnt, z_pool,
                                                                 (float*)d_out, nB * DD);
}

// Round 13
// 234.543 us; speedup vs baseline: 1.0742x; 1.0742x over previous
//
#include <hip/hip_runtime.h>
#include <cfloat>

#define DD 128
#define NLAYERS 3
#define NPB 128     // nodes per block in pool stage A
#define SCHUNK 1024 // elements per block in hierarchical scan

typedef short bf16x8 __attribute__((ext_vector_type(8)));
typedef float f32x4 __attribute__((ext_vector_type(4)));

// ---- bf16 helpers (RNE) ----
__device__ __forceinline__ unsigned short f2b(float f) {
    unsigned u = __float_as_uint(f);
    u += 0x7fffu + ((u >> 16) & 1u);
    return (unsigned short)(u >> 16);
}
__device__ __forceinline__ float b2f(unsigned short b) {
    return __uint_as_float(((unsigned)b) << 16);
}

// ---- monotonic float<->uint encoding for atomicMax on floats ----
__device__ __forceinline__ unsigned enc_f(float f) {
    unsigned b = __float_as_uint(f);
    return (b & 0x80000000u) ? ~b : (b | 0x80000000u);
}
__device__ __forceinline__ float dec_f(unsigned u) {
    return __uint_as_float((u & 0x80000000u) ? (u & 0x7fffffffu) : ~u);
}

// ========== conversion (x + W1 + W2) and workspace zeroing, ONE kernel ==========
__global__ void convert_init_kernel(const float* __restrict__ x_in,
                                    unsigned short* __restrict__ xb,
                                    const float* __restrict__ W1s, const float* __restrict__ W2s,
                                    unsigned short* __restrict__ Wb1s,
                                    unsigned short* __restrict__ Wb2s,
                                    int* __restrict__ deg,
                                    float* __restrict__ ps, unsigned* __restrict__ pmx,
                                    int* __restrict__ cnt,
                                    int n4, int nN, int nBD, int nB, int per, int xbBlocks) {
    if ((int)blockIdx.x < xbBlocks) {
        int i = blockIdx.x * 256 + threadIdx.x;
        if (i < n4) {
            float4 v = ((const float4*)x_in)[i];
            ushort4 b;
            b.x = f2b(v.x); b.y = f2b(v.y); b.z = f2b(v.z); b.w = f2b(v.w);
            ((ushort4*)xb)[i] = b;
        }
        if (i < nN) deg[i] = 0;
        if (i < nBD) { ps[i] = 0.f; pmx[i] = 0u; }   // 0 < enc(any finite)
        if (i < nB) cnt[i] = 0;
    } else {
        int idx = (blockIdx.x - xbBlocks) * 256 + threadIdx.x;
        if (idx >= 2 * per) return;
        const float* W = (idx < per) ? W1s : W2s;
        unsigned short* Wb = (idx < per) ? Wb1s : Wb2s;
        if (idx >= per) idx -= per;
        int lane = idx & 63;
        int rest = idx >> 6;
        int ks = rest & 3; rest >>= 2;
        int nt = rest & 7;
        int l  = rest >> 3;
        int n = nt * 16 + (lane & 15);
        int kbase = ks * 32 + (lane >> 4) * 8;
        const float* Wl = W + (size_t)l * DD * DD;
        unsigned short* dst = Wb + (size_t)l * DD * DD + ((size_t)(nt * 4 + ks) * 64 + lane) * 8;
#pragma unroll
        for (int j = 0; j < 8; ++j) dst[j] = f2b(Wl[(size_t)(kbase + j) * DD + n]);
    }
}

// ================= CSR build =================

__global__ void deg_kernel(const int* __restrict__ dst, int* __restrict__ deg, int nE) {
    int e = blockIdx.x * blockDim.x + threadIdx.x;
    if (e < nE) atomicAdd(&deg[dst[e]], 1);
}

__global__ __launch_bounds__(256) void scan_sum_kernel(const int* __restrict__ deg,
                                                       int* __restrict__ bsum, int nN) {
    int t = threadIdx.x;
    int base = blockIdx.x * SCHUNK + t * 4;
    int v = 0;
#pragma unroll
    for (int k = 0; k < 4; ++k) { int i = base + k; if (i < nN) v += deg[i]; }
    for (int off = 32; off; off >>= 1) v += __shfl_down(v, off, 64);
    __shared__ int wsum[4];
    if ((t & 63) == 0) wsum[t >> 6] = v;
    __syncthreads();
    if (t == 0) bsum[blockIdx.x] = wsum[0] + wsum[1] + wsum[2] + wsum[3];
}

__global__ __launch_bounds__(256) void scan_apply_kernel(const int* __restrict__ deg,
                                                         const int* __restrict__ bsum,
                                                         int* __restrict__ row_ptr,
                                                         int nN, int G) {
    __shared__ int sh[256];
    __shared__ int sh2[256];
    int t = threadIdx.x;
    int base = blockIdx.x * SCHUNK + t * 4;
    int d0 = 0, d1 = 0, d2 = 0, d3 = 0;
    if (base + 0 < nN) d0 = deg[base + 0];
    if (base + 1 < nN) d1 = deg[base + 1];
    if (base + 2 < nN) d2 = deg[base + 2];
    if (base + 3 < nN) d3 = deg[base + 3];
    int tsum = d0 + d1 + d2 + d3;
    sh[t] = tsum;
    sh2[t] = (t < G) ? bsum[t] : 0;
    __syncthreads();
    for (int off = 1; off < 256; off <<= 1) {
        int o  = (t >= off) ? sh[t - off]  : 0;
        int o2 = (t >= off) ? sh2[t - off] : 0;
        __syncthreads();
        sh[t] += o; sh2[t] += o2;
        __syncthreads();
    }
    int bb = (blockIdx.x > 0) ? sh2[blockIdx.x - 1] : 0;  // exclusive block offset
    int run = bb + sh[t] - tsum;
    if (base + 0 < nN) row_ptr[base + 0] = run;           run += d0;
    if (base + 1 < nN) row_ptr[base + 1] = run;           run += d1;
    if (base + 2 < nN) row_ptr[base + 2] = run;           run += d2;
    if (base + 3 < nN) row_ptr[base + 3] = run;
    if (blockIdx.x == G - 1 && t == 0) row_ptr[nN] = sh2[G - 1];
}

// slot = row_ptr[d] + atomicSub(deg[d]) - 1  (deg is dead after the scan; ends at 0)
__global__ void fill_kernel(const int* __restrict__ src, const int* __restrict__ dst,
                            const int* __restrict__ row_ptr, int* __restrict__ deg,
                            int* __restrict__ csr_src, int nE) {
    int e = blockIdx.x * blockDim.x + threadIdx.x;
    if (e >= nE) return;
    int d = dst[e];
    int pos = row_ptr[d] + atomicSub(&deg[d], 1) - 1;
    csr_src[pos] = src[e];
}

// ====== aggregation + combine (bf16-only, 32 lanes/node, 8-wide clamped ILP) ======
// h0b = xb[n] + (za0 + za1/degc) * sum + za2 * (deg>0 ? max : 0)
__global__ __launch_bounds__(256) void agg_combine_kernel(const unsigned short* __restrict__ xb,
                                                          const int* __restrict__ csr_src,
                                                          const int* __restrict__ row_ptr,
                                                          const float* __restrict__ z_agg_l,
                                                          unsigned short* __restrict__ h0b,
                                                          int nN) {
    int t = threadIdx.x;
    int n = blockIdx.x * 8 + (t >> 5);
    if (n >= nN) return;
    int q = t & 31;
    int start = row_ptr[n], end = row_ptr[n + 1];
    float za0 = z_agg_l[0], za1 = z_agg_l[1], za2 = z_agg_l[2];

    const ushort4* tab = (const ushort4*)xb;
    float4 sum = make_float4(0.f, 0.f, 0.f, 0.f);
    float4 mx  = make_float4(-FLT_MAX, -FLT_MAX, -FLT_MAX, -FLT_MAX);
    int last = end - 1;
    for (int e = start; e < end; e += 8) {
        // 8 clamped gathers always in flight; max is duplicate-safe, sum predicated
        int s0 = csr_src[e];
        int s1 = csr_src[e + 1 <= last ? e + 1 : last];
        int s2 = csr_src[e + 2 <= last ? e + 2 : last];
        int s3 = csr_src[e + 3 <= last ? e + 3 : last];
        int s4 = csr_src[e + 4 <= last ? e + 4 : last];
        int s5 = csr_src[e + 5 <= last ? e + 5 : last];
        int s6 = csr_src[e + 6 <= last ? e + 6 : last];
        int s7 = csr_src[e + 7 <= last ? e + 7 : last];
        ushort4 v0 = tab[(size_t)s0 * 32 + q];
        ushort4 v1 = tab[(size_t)s1 * 32 + q];
        ushort4 v2 = tab[(size_t)s2 * 32 + q];
        ushort4 v3 = tab[(size_t)s3 * 32 + q];
        ushort4 v4 = tab[(size_t)s4 * 32 + q];
        ushort4 v5 = tab[(size_t)s5 * 32 + q];
        ushort4 v6 = tab[(size_t)s6 * 32 + q];
        ushort4 v7 = tab[(size_t)s7 * 32 + q];
#define ACCP(vb, ok) { float ax=b2f(vb.x),ay=b2f(vb.y),az=b2f(vb.z),aw=b2f(vb.w); \
                  mx.x=fmaxf(mx.x,ax);mx.y=fmaxf(mx.y,ay); \
                  mx.z=fmaxf(mx.z,az);mx.w=fmaxf(mx.w,aw); \
                  if (ok) { sum.x+=ax;sum.y+=ay;sum.z+=az;sum.w+=aw; } }
        ACCP(v0, true)
        ACCP(v1, e + 1 < end)
        ACCP(v2, e + 2 < end)
        ACCP(v3, e + 3 < end)
        ACCP(v4, e + 4 < end)
        ACCP(v5, e + 5 < end)
        ACCP(v6, e + 6 < end)
        ACCP(v7, e + 7 < end)
#undef ACCP
    }
    int degn = end - start;
    float inv = 1.0f / fmaxf((float)degn, 1.0f);
    float c01 = za0 + za1 * inv;
    bool nb = (degn > 0);
    ushort4 sb = tab[(size_t)n * 32 + q];
    ushort4 r;
    r.x = f2b(b2f(sb.x) + c01 * sum.x + za2 * (nb ? mx.x : 0.f));
    r.y = f2b(b2f(sb.y) + c01 * sum.y + za2 * (nb ? mx.y : 0.f));
    r.z = f2b(b2f(sb.z) + c01 * sum.z + za2 * (nb ? mx.z : 0.f));
    r.w = f2b(b2f(sb.w) + c01 * sum.w + za2 * (nb ? mx.w : 0.f));
    ((ushort4*)(h0b + (size_t)n * DD))[q] = r;
}

// ================= fused FFN: xb_out = xb_in + relu(relu(h0@W1+b1)@W2+b2) ======
// Block = 64 rows, 4 waves, each wave owns a 16-row strip.
// LDS union (32 KiB): first 16 KiB = h1 bf16 [64 x 256B]; whole = v f32 [64 x 512B].
__global__ __launch_bounds__(256) void fused_ffn_kernel(
        const unsigned short* __restrict__ h0b,
        const unsigned short* __restrict__ Wb1, const float* __restrict__ b1,
        const unsigned short* __restrict__ Wb2, const float* __restrict__ b2,
        const unsigned short* __restrict__ xb_in,
        unsigned short* __restrict__ xb_out, int M) {
    __shared__ char lds[64 * DD * 4];        // 32 KiB union

    int t = threadIdx.x;
    int lane = t & 63;
    int w = t >> 6;
    int row0 = blockIdx.x * 64;
    int ar = row0 + w * 16 + (lane & 15);
    if (ar > M - 1) ar = M - 1;              // clamp loads; epilogue guards stores
    int g = lane >> 4;                       // k-group 0..3
    int colw = lane & 15;
    int rbl = w * 16 + g * 4;                // local C-row base

    const unsigned short* Ap = h0b + (size_t)ar * DD + g * 8;
    bf16x8 a0 = *(const bf16x8*)(Ap);
    bf16x8 a1 = *(const bf16x8*)(Ap + 32);
    bf16x8 a2 = *(const bf16x8*)(Ap + 64);
    bf16x8 a3 = *(const bf16x8*)(Ap + 96);

    // ---- GEMM1 -> h1 (bf16, LDS, swizzled) ----
    const bf16x8* Wv1 = (const bf16x8*)Wb1;
#pragma unroll
    for (int nt = 0; nt < 8; ++nt) {
        f32x4 acc = {0.f, 0.f, 0.f, 0.f};
        acc = __builtin_amdgcn_mfma_f32_16x16x32_bf16(a0, Wv1[(nt * 4 + 0) * 64 + lane], acc, 0, 0, 0);
        acc = __builtin_amdgcn_mfma_f32_16x16x32_bf16(a1, Wv1[(nt * 4 + 1) * 64 + lane], acc, 0, 0, 0);
        acc = __builtin_amdgcn_mfma_f32_16x16x32_bf16(a2, Wv1[(nt * 4 + 2) * 64 + lane], acc, 0, 0, 0);
        acc = __builtin_amdgcn_mfma_f32_16x16x32_bf16(a3, Wv1[(nt * 4 + 3) * 64 + lane], acc, 0, 0, 0);
        float bv = b1[nt * 16 + colw];
        int cb = (nt * 16 + colw) * 2;
#pragma unroll
        for (int i = 0; i < 4; ++i) {
            int r1 = rbl + i;
            *(unsigned short*)(lds + r1 * 256 + (cb ^ ((unsigned)(r1 & 7) << 4))) =
                f2b(fmaxf(acc[i] + bv, 0.f));
        }
    }

    // ---- h1 A-fragments from own strip (in-wave RAW through LDS) ----
    int rAl = w * 16 + (lane & 15);
    unsigned swA = (unsigned)(rAl & 7) << 4;
    const char* hA = lds + rAl * 256;
    bf16x8 c0 = *(const bf16x8*)(hA + ((g * 16 +   0) ^ swA));
    bf16x8 c1 = *(const bf16x8*)(hA + ((g * 16 +  64) ^ swA));
    bf16x8 c2 = *(const bf16x8*)(hA + ((g * 16 + 128) ^ swA));
    bf16x8 c3 = *(const bf16x8*)(hA + ((g * 16 + 192) ^ swA));
    __syncthreads();   // all c-frags loaded before v aliases h1 storage

    // ---- GEMM2 -> v = relu(h1@W2+b2) (f32, LDS, swizzled) ----
    const bf16x8* Wv2 = (const bf16x8*)Wb2;
#pragma unroll
    for (int nt = 0; nt < 8; ++nt) {
        f32x4 acc = {0.f, 0.f, 0.f, 0.f};
        acc = __builtin_amdgcn_mfma_f32_16x16x32_bf16(c0, Wv2[(nt * 4 + 0) * 64 + lane], acc, 0, 0, 0);
        acc = __builtin_amdgcn_mfma_f32_16x16x32_bf16(c1, Wv2[(nt * 4 + 1) * 64 + lane], acc, 0, 0, 0);
        acc = __builtin_amdgcn_mfma_f32_16x16x32_bf16(c2, Wv2[(nt * 4 + 2) * 64 + lane], acc, 0, 0, 0);
        acc = __builtin_amdgcn_mfma_f32_16x16x32_bf16(c3, Wv2[(nt * 4 + 3) * 64 + lane], acc, 0, 0, 0);
        float bv = b2[nt * 16 + colw];
        int cb = (nt * 16 + colw) * 4;
#pragma unroll
        for (int i = 0; i < 4; ++i) {
            int r1 = rbl + i;
            *(float*)(lds + r1 * 512 + (cb ^ ((unsigned)(r1 & 7) << 4))) =
                fmaxf(acc[i] + bv, 0.f);
        }
    }
    __syncthreads();

    // ---- coalesced epilogue: xb_out = bf16(xb_in + v) ----
    int q = t & 31;
    int grp = t >> 5;
    for (int pass = 0; pass < 8; ++pass) {
        int rr = pass * 8 + grp;
        int n = row0 + rr;
        if (n < M) {
            ushort4 xv = ((const ushort4*)(xb_in + (size_t)n * DD))[q];
            float4 vv = *(const float4*)(lds + rr * 512 + ((q * 16) ^ ((unsigned)(rr & 7) << 4)));
            ushort4 b;
            b.x = f2b(b2f(xv.x) + vv.x);
            b.y = f2b(b2f(xv.y) + vv.y);
            b.z = f2b(b2f(xv.z) + vv.z);
            b.w = f2b(b2f(xv.w) + vv.w);
            ((ushort4*)(xb_out + (size_t)n * DD))[q] = b;
        }
    }
}

// ================= global pooling, two-stage (bf16 input) =================
__global__ __launch_bounds__(256) void pool_partial_kernel(const unsigned short* __restrict__ xb,
                                                           const int* __restrict__ batch,
                                                           float* __restrict__ ps,
                                                           unsigned* __restrict__ pmx,
                                                           int* __restrict__ cnt, int nN) {
    int t = threadIdx.x;
    int q = t & 31;
    int p = t >> 5;
    int node0 = blockIdx.x * NPB;
    int nodeEnd = node0 + NPB; if (nodeEnd > nN) nodeEnd = nN;

    const ushort4* xv = (const ushort4*)xb;
    float4 sum = make_float4(0.f, 0.f, 0.f, 0.f);
    float4 mx  = make_float4(-FLT_MAX, -FLT_MAX, -FLT_MAX, -FLT_MAX);
    int count = 0, g_cur = -1;

    for (int row = node0 + p; row < nodeEnd; row += 8) {
        int g = batch[row];
        if (g != g_cur) {
            if (g_cur >= 0) {
                atomicAdd(&ps[(size_t)g_cur * DD + q * 4 + 0], sum.x);
                atomicAdd(&ps[(size_t)g_cur * DD + q * 4 + 1], sum.y);
                atomicAdd(&ps[(size_t)g_cur * DD + q * 4 + 2], sum.z);
                atomicAdd(&ps[(size_t)g_cur * DD + q * 4 + 3], sum.w);
                atomicMax(&pmx[(size_t)g_cur * DD + q * 4 + 0], enc_f(mx.x));
                atomicMax(&pmx[(size_t)g_cur * DD + q * 4 + 1], enc_f(mx.y));
                atomicMax(&pmx[(size_t)g_cur * DD + q * 4 + 2], enc_f(mx.z));
                atomicMax(&pmx[(size_t)g_cur * DD + q * 4 + 3], enc_f(mx.w));
                if (q == 0) atomicAdd(&cnt[g_cur], count);
            }
            sum = make_float4(0.f, 0.f, 0.f, 0.f);
            mx  = make_float4(-FLT_MAX, -FLT_MAX, -FLT_MAX, -FLT_MAX);
            count = 0; g_cur = g;
        }
        ushort4 vb = xv[(size_t)row * 32 + q];
        float vx = b2f(vb.x), vy = b2f(vb.y), vz = b2f(vb.z), vw = b2f(vb.w);
        sum.x += vx; sum.y += vy; sum.z += vz; sum.w += vw;
        mx.x = fmaxf(mx.x, vx); mx.y = fmaxf(mx.y, vy);
        mx.z = fmaxf(mx.z, vz); mx.w = fmaxf(mx.w, vw);
        count++;
    }
    if (g_cur >= 0) {
        atomicAdd(&ps[(size_t)g_cur * DD + q * 4 + 0], sum.x);
        atomicAdd(&ps[(size_t)g_cur * DD + q * 4 + 1], sum.y);
        atomicAdd(&ps[(size_t)g_cur * DD + q * 4 + 2], sum.z);
        atomicAdd(&ps[(size_t)g_cur * DD + q * 4 + 3], sum.w);
        atomicMax(&pmx[(size_t)g_cur * DD + q * 4 + 0], enc_f(mx.x));
        atomicMax(&pmx[(size_t)g_cur * DD + q * 4 + 1], enc_f(mx.y));
        atomicMax(&pmx[(size_t)g_cur * DD + q * 4 + 2], enc_f(mx.z));
        atomicMax(&pmx[(size_t)g_cur * DD + q * 4 + 3], enc_f(mx.w));
        if (q == 0) atomicAdd(&cnt[g_cur], count);
    }
}

__global__ void pool_final_kernel(const float* __restrict__ ps,
                                  const unsigned* __restrict__ pmx,
                                  const int* __restrict__ cnt,
                                  const float* __restrict__ z_pool,
                                  float* __restrict__ out, int total) {
    int i = blockIdx.x * blockDim.x + threadIdx.x;
    if (i >= total) return;
    int g = i >> 7;
    float zp0 = z_pool[0], zp1 = z_pool[1], zp2 = z_pool[2];
    int c = cnt[g];
    float s = ps[i];
    float pm = s / fmaxf((float)c, 1.0f);
    float pv = (c > 0) ? dec_f(pmx[i]) : 0.0f;
    out[i] = zp0 * s + zp1 * pm + zp2 * pv;
}

extern "C" void kernel_launch(void* const* d_in, const int* in_sizes, int n_in,
                              void* d_out, int out_size, void* d_ws, size_t ws_size,
                              hipStream_t stream) {
    const float* x_in   = (const float*)d_in[0];
    const int*   eidx   = (const int*)d_in[1];
    const int*   batch  = (const int*)d_in[2];
    const float* z_agg  = (const float*)d_in[3];
    const float* z_pool = (const float*)d_in[4];
    const float* W1     = (const float*)d_in[5];
    const float* b1     = (const float*)d_in[6];
    const float* W2     = (const float*)d_in[7];
    const float* b2     = (const float*)d_in[8];

    int nN = in_sizes[0] / DD;       // 50000
    int nE = in_sizes[1] / 2;        // 600000
    int nB = out_size / DD;          // 64
    const int* src = eidx;
    const int* dst = eidx + nE;

    char* p = (char*)d_ws;
    size_t nd = (size_t)nN * DD * sizeof(float);
    unsigned short* xb0 = (unsigned short*)p;  p += nd / 2;
    unsigned short* xbA = (unsigned short*)p;  p += nd / 2;
    unsigned short* h0b = (unsigned short*)p;  p += nd / 2;
    unsigned short* Wb1 = (unsigned short*)p;  p += (size_t)NLAYERS * DD * DD * 2;
    unsigned short* Wb2 = (unsigned short*)p;  p += (size_t)NLAYERS * DD * DD * 2;
    int* row_ptr = (int*)p;  p += (size_t)(nN + 1) * 4;
    int* deg     = (int*)p;  p += (size_t)nN * 4;
    int* csr_src = (int*)p;  p += (size_t)nE * 4 + 64;   // +64B slack
    float*    ps  = (float*)p;    p += (size_t)nB * DD * 4;
    unsigned* pmx = (unsigned*)p; p += (size_t)nB * DD * 4;
    int*      cnt = (int*)p;      p += (size_t)nB * 4;
    int*      bsum = (int*)p;

    int G = (nN + SCHUNK - 1) / SCHUNK;   // 49 for nN=50000

    // ---- conversion + zero-init (one launch) ----
    int n4 = nN * DD / 4;
    int per = NLAYERS * 8 * 4 * 64;
    int xbBlocks = (n4 + 255) / 256;
    int wBlocks = (2 * per + 255) / 256;
    convert_init_kernel<<<xbBlocks + wBlocks, 256, 0, stream>>>(
        x_in, xb0, W1, W2, Wb1, Wb2, deg, ps, pmx, cnt,
        n4, nN, nB * DD, nB, per, xbBlocks);

    // ---- CSR build (deg -> scan -> fill; fill consumes deg) ----
    deg_kernel<<<(nE + 255) / 256, 256, 0, stream>>>(dst, deg, nE);
    scan_sum_kernel<<<G, 256, 0, stream>>>(deg, bsum, nN);
    scan_apply_kernel<<<G, 256, 0, stream>>>(deg, bsum, row_ptr, nN, G);
    fill_kernel<<<(nE + 255) / 256, 256, 0, stream>>>(src, dst, row_ptr, deg, csr_src, nE);

    // ---- layers ----
    int agrid = (nN + 7) / 8;
    int fgrid = (nN + 63) / 64;
    // L0: xb0 -> xbA
    agg_combine_kernel<<<agrid, 256, 0, stream>>>(xb0, csr_src, row_ptr, z_agg + 0, h0b, nN);
    fused_ffn_kernel<<<fgrid, 256, 0, stream>>>(h0b, Wb1 + 0 * DD * DD, b1 + 0 * DD,
                                                Wb2 + 0 * DD * DD, b2 + 0 * DD,
                                                xb0, xbA, nN);
    // L1: xbA -> xb0
    agg_combine_kernel<<<agrid, 256, 0, stream>>>(xbA, csr_src, row_ptr, z_agg + 3, h0b, nN);
    fused_ffn_kernel<<<fgrid, 256, 0, stream>>>(h0b, Wb1 + 1 * DD * DD, b1 + 1 * DD,
                                                Wb2 + 1 * DD * DD, b2 + 1 * DD,
                                                xbA, xb0, nN);
    // L2: xb0 -> xbA
    agg_combine_kernel<<<agrid, 256, 0, stream>>>(xb0, csr_src, row_ptr, z_agg + 6, h0b, nN);
    fused_ffn_kernel<<<fgrid, 256, 0, stream>>>(h0b, Wb1 + 2 * DD * DD, b1 + 2 * DD,
                                                Wb2 + 2 * DD * DD, b2 + 2 * DD,
                                                xb0, xbA, nN);

    // ---- pooling ----
    pool_partial_kernel<<<(nN + NPB - 1) / NPB, 256, 0, stream>>>(xbA, batch, ps, pmx, cnt, nN);
    pool_final_kernel<<<(nB * DD + 255) / 256, 256, 0, stream>>>(ps, pmx, cnt, z_pool,
                                                                 (float*)d_out, nB * DD);
}